// Round 1
// baseline (2255.229 us; speedup 1.0000x reference)
//
#include <hip/hip_runtime.h>

#define BATCH 32
#define NV    10242
#define NF    20480
#define NBB   64          // 2 hemis * 32 batches ; lane = bb
#define NSTEPS 10
#define STEPSZ 0.1f
#define EPSV   1e-8f

// ---------------- workspace layout: float4-vectorized, lane = bb ----------------
// v    : [NV][NBB] float4   (x, y, z, sulc)
// feat : [NV][3][NBB] float4 (g0: pos+pad, g1: normal+pad, g2: 0.5*lap+pad)
// h    : [NV][4][NBB] float4 (16 channels)
static constexpr size_t OFF_V    = 0;                                  // floats
static constexpr size_t OFF_FEAT = OFF_V    + (size_t)NV * NBB * 4;
static constexpr size_t OFF_H    = OFF_FEAT + (size_t)NV * NBB * 12;
static constexpr size_t OFF_CSZ  = OFF_H    + (size_t)NV * NBB * 16;   // [6][NBB] ctr(3),size(3)
static constexpr size_t OFF_INT  = OFF_CSZ  + 6 * NBB;
// int region: deg[NV], nbrB[NV*6], nbrC[NV*6]

__device__ __forceinline__ int rfl(int x) { return __builtin_amdgcn_readfirstlane(x); }

// bijective XCD chunking swizzle (contiguous vertex range per XCD; same mapping in
// geom/layer1/layer2 so cross-kernel L2 reuse lands on the same XCD)
__device__ __forceinline__ int swz(int b, int n) {
    int q = n >> 3, r = n & 7;
    int x = b & 7, i = b >> 3;
    return (x < r ? x * (q + 1) : r * (q + 1) + (x - r) * q) + i;
}

// ---------------- adjacency build (once per launch) ----------------
__global__ __launch_bounds__(256) void k_zero(int* p, int n) {
    int i = blockIdx.x * 256 + threadIdx.x;
    if (i < n) p[i] = 0;   // zeroing nbrB/nbrC too makes slot-k loads safe for deg<6 verts
}

__global__ __launch_bounds__(256) void k_build(const int* __restrict__ faces,
                                               int* deg, int* nbrB, int* nbrC) {
    int fi = blockIdx.x * 256 + threadIdx.x;
    if (fi >= NF) return;
    int vv[3] = {faces[fi * 3 + 0], faces[fi * 3 + 1], faces[fi * 3 + 2]};
#pragma unroll
    for (int c = 0; c < 3; c++) {
        int vtx = vv[c];
        int s = atomicAdd(&deg[vtx], 1);
        nbrB[vtx * 6 + s] = vv[(c + 1) % 3];   // next corner = dedup'd neighbor
        nbrC[vtx * 6 + s] = vv[(c + 2) % 3];   // prev corner
    }
}

// ---------------- bbox + normalize + transpose-in (one block per bb) ----------------
__global__ __launch_bounds__(256) void k_norm(const float* __restrict__ lh,
                                              const float* __restrict__ rh,
                                              float4* __restrict__ v4,
                                              float* __restrict__ csz) {
    int bb = blockIdx.x;
    const float* src = (bb < BATCH) ? (lh + (size_t)bb * NV * 3)
                                    : (rh + (size_t)(bb - BATCH) * NV * 3);
    __shared__ float smin[3][256], smax[3][256];
    float mn[3] = {1e30f, 1e30f, 1e30f}, mx[3] = {-1e30f, -1e30f, -1e30f};
    for (int i = threadIdx.x; i < NV; i += 256) {
#pragma unroll
        for (int c = 0; c < 3; c++) {
            float x = src[i * 3 + c];
            mn[c] = fminf(mn[c], x);
            mx[c] = fmaxf(mx[c], x);
        }
    }
#pragma unroll
    for (int c = 0; c < 3; c++) { smin[c][threadIdx.x] = mn[c]; smax[c][threadIdx.x] = mx[c]; }
    __syncthreads();
    for (int s = 128; s > 0; s >>= 1) {
        if (threadIdx.x < s) {
#pragma unroll
            for (int c = 0; c < 3; c++) {
                smin[c][threadIdx.x] = fminf(smin[c][threadIdx.x], smin[c][threadIdx.x + s]);
                smax[c][threadIdx.x] = fmaxf(smax[c][threadIdx.x], smax[c][threadIdx.x + s]);
            }
        }
        __syncthreads();
    }
    float ctr[3], sz[3];
#pragma unroll
    for (int c = 0; c < 3; c++) {
        ctr[c] = 0.5f * (smin[c][0] + smax[c][0]);
        sz[c]  = smax[c][0] - ctr[c];
    }
    if (threadIdx.x == 0) {
#pragma unroll
        for (int c = 0; c < 3; c++) { csz[c * NBB + bb] = ctr[c]; csz[(3 + c) * NBB + bb] = sz[c]; }
    }
    for (int i = threadIdx.x; i < NV; i += 256) {
        float4 o;
        o.x = (src[i * 3 + 0] - ctr[0]) / sz[0];
        o.y = (src[i * 3 + 1] - ctr[1]) / sz[1];
        o.z = (src[i * 3 + 2] - ctr[2]) / sz[2];
        o.w = 0.f;                               // sulc lives in v.w
        v4[(size_t)i * NBB + bb] = o;
    }
}

// ---------------- per-step: geometry -> feat = (v | n | 0.5*lap), float4 groups ----------------
__global__ __launch_bounds__(256, 4) void k_geom(const float4* __restrict__ v4,
                                                 const int* __restrict__ deg,
                                                 const int* __restrict__ nbrB,
                                                 const int* __restrict__ nbrC,
                                                 float4* __restrict__ feat4) {
    int lane = threadIdx.x & 63;
    int blk = swz(blockIdx.x, gridDim.x);
    int vi = rfl(blk * 4 + (threadIdx.x >> 6));
    if (vi >= NV) return;
    float sgn = (lane < BATCH) ? 1.f : -1.f;   // rh: reversed winding flips face normals
    float4 a = v4[(size_t)vi * NBB + lane];
    int d = rfl(deg[vi]);
    float vnx = 0.f, vny = 0.f, vnz = 0.f, lx = 0.f, ly = 0.f, lz = 0.f;

    auto acc = [&](float4 b, float4 c) {
        float e1x = b.x - a.x, e1y = b.y - a.y, e1z = b.z - a.z;   // B - A
        float e2x = c.x - a.x, e2y = c.y - a.y, e2z = c.z - a.z;   // C - A
        float fnx = e1y * e2z - e1z * e2y;                         // face normal
        float fny = e1z * e2x - e1x * e2z;
        float fnz = e1x * e2y - e1y * e2x;
        vnx += fnx; vny += fny; vnz += fnz;
        float rd = 1.f / (sqrtf(fnx * fnx + fny * fny + fnz * fnz) + EPSV);
        float ux = c.x - b.x, uy = c.y - b.y, uz = c.z - b.z;
        float wx = a.x - b.x, wy = a.y - b.y, wz = a.z - b.z;
        float cB = (ux * wx + uy * wy + uz * wz) * rd;             // cot at B
        float rx = a.x - c.x, ry = a.y - c.y, rz = a.z - c.z;
        float sx = b.x - c.x, sy = b.y - c.y, sz2 = b.z - c.z;
        float cC = (rx * sx + ry * sy + rz * sz2) * rd;            // cot at C
        lx += cC * e1x + cB * e2x;
        ly += cC * e1y + cB * e2y;
        lz += cC * e1z + cB * e2z;
    };

    if (d == 6) {
        int ib[6], ic[6];
#pragma unroll
        for (int k = 0; k < 6; k++) {
            ib[k] = rfl(nbrB[vi * 6 + k]);
            ic[k] = rfl(nbrC[vi * 6 + k]);
        }
        float4 pb[6], pc[6];
#pragma unroll
        for (int k = 0; k < 6; k++) {          // all 12 loads batched in flight
            pb[k] = v4[(size_t)ib[k] * NBB + lane];
            pc[k] = v4[(size_t)ic[k] * NBB + lane];
        }
#pragma unroll
        for (int k = 0; k < 6; k++) acc(pb[k], pc[k]);
    } else {
        for (int k = 0; k < d; k++) {
            int iB = rfl(nbrB[vi * 6 + k]);
            int iC = rfl(nbrC[vi * 6 + k]);
            acc(v4[(size_t)iB * NBB + lane], v4[(size_t)iC * NBB + lane]);
        }
    }
    vnx *= sgn; vny *= sgn; vnz *= sgn;
    float nn = 1.f / (sqrtf(vnx * vnx + vny * vny + vnz * vnz) + EPSV);
    float4* fp = feat4 + (size_t)vi * 3 * NBB + lane;
    fp[0 * NBB] = make_float4(a.x, a.y, a.z, 0.f);
    fp[1 * NBB] = make_float4(vnx * nn, vny * nn, vnz * nn, 0.f);
    fp[2 * NBB] = make_float4(0.5f * lx, 0.5f * ly, 0.5f * lz, 0.f);
}

// ---------------- per-step: layer1  h = relu(feat@W1s + mean_nbr(feat)@W1n + b1) ----------------
__global__ __launch_bounds__(256, 4) void k_layer1(const float4* __restrict__ feat4,
                                                   const int* __restrict__ deg,
                                                   const int* __restrict__ nbrB,
                                                   const float* __restrict__ W1s,
                                                   const float* __restrict__ W1n,
                                                   const float* __restrict__ b1,
                                                   float4* __restrict__ h4) {
    __shared__ float sWs[144], sWn[144], sb[16];
    int t = threadIdx.x;
    if (t < 144) { sWs[t] = W1s[t]; sWn[t] = W1n[t]; }
    if (t < 16) sb[t] = b1[t];
    __syncthreads();
    int lane = t & 63;
    int blk = swz(blockIdx.x, gridDim.x);
    int vi = rfl(blk * 4 + (t >> 6));
    if (vi >= NV) return;
    const float4* fo = feat4 + (size_t)vi * 3 * NBB + lane;
    float4 f0 = fo[0 * NBB], f1 = fo[1 * NBB], f2 = fo[2 * NBB];
    float own[9] = {f0.x, f0.y, f0.z, f1.x, f1.y, f1.z, f2.x, f2.y, f2.z};
    float m[9] = {0.f, 0.f, 0.f, 0.f, 0.f, 0.f, 0.f, 0.f, 0.f};
    int d = rfl(deg[vi]);
    if (d == 6) {
        int ib[6];
#pragma unroll
        for (int k = 0; k < 6; k++) ib[k] = rfl(nbrB[vi * 6 + k]);
#pragma unroll
        for (int k = 0; k < 6; k++) {
            const float4* fu = feat4 + (size_t)ib[k] * 3 * NBB + lane;
            float4 a0 = fu[0 * NBB], a1 = fu[1 * NBB], a2 = fu[2 * NBB];
            m[0] += a0.x; m[1] += a0.y; m[2] += a0.z;
            m[3] += a1.x; m[4] += a1.y; m[5] += a1.z;
            m[6] += a2.x; m[7] += a2.y; m[8] += a2.z;
        }
    } else {
        for (int k = 0; k < d; k++) {
            const float4* fu = feat4 + (size_t)rfl(nbrB[vi * 6 + k]) * 3 * NBB + lane;
            float4 a0 = fu[0 * NBB], a1 = fu[1 * NBB], a2 = fu[2 * NBB];
            m[0] += a0.x; m[1] += a0.y; m[2] += a0.z;
            m[3] += a1.x; m[4] += a1.y; m[5] += a1.z;
            m[6] += a2.x; m[7] += a2.y; m[8] += a2.z;
        }
    }
    float inv = 1.f / (float)d;
#pragma unroll
    for (int i = 0; i < 9; i++) m[i] *= inv;
    float hv[16];
#pragma unroll
    for (int j = 0; j < 16; j++) {
        float acc = sb[j];
#pragma unroll
        for (int i = 0; i < 9; i++) acc += own[i] * sWs[i * 16 + j] + m[i] * sWn[i * 16 + j];
        hv[j] = fmaxf(acc, 0.f);
    }
    float4* hp = h4 + (size_t)vi * 4 * NBB + lane;
#pragma unroll
    for (int g = 0; g < 4; g++)
        hp[g * NBB] = make_float4(hv[g * 4 + 0], hv[g * 4 + 1], hv[g * 4 + 2], hv[g * 4 + 3]);
}

// ---------------- per-step: layer2 + output head + state update (sulc in v.w) ----------------
__global__ __launch_bounds__(256, 4) void k_layer2(const float4* __restrict__ h4,
                                                   const float4* __restrict__ feat4,
                                                   const int* __restrict__ deg,
                                                   const int* __restrict__ nbrB,
                                                   const float* __restrict__ W2s,
                                                   const float* __restrict__ W2n,
                                                   const float* __restrict__ b2,
                                                   const float* __restrict__ Wo,
                                                   const float* __restrict__ bo,
                                                   float4* __restrict__ v4) {
    __shared__ float sWs[256], sWn[256], sb[16], sWo[48], sbo[3];
    int t = threadIdx.x;
    sWs[t] = W2s[t];
    sWn[t] = W2n[t];
    if (t < 16) sb[t] = b2[t];
    if (t < 48) sWo[t] = Wo[t];
    if (t < 3) sbo[t] = bo[t];
    __syncthreads();
    int lane = t & 63;
    int blk = swz(blockIdx.x, gridDim.x);
    int vi = rfl(blk * 4 + (t >> 6));
    if (vi >= NV) return;
    const float4* ho = h4 + (size_t)vi * 4 * NBB + lane;
    float own[16], m[16];
#pragma unroll
    for (int g = 0; g < 4; g++) {
        float4 o = ho[g * NBB];
        own[g * 4 + 0] = o.x; own[g * 4 + 1] = o.y; own[g * 4 + 2] = o.z; own[g * 4 + 3] = o.w;
        m[g * 4 + 0] = 0.f; m[g * 4 + 1] = 0.f; m[g * 4 + 2] = 0.f; m[g * 4 + 3] = 0.f;
    }
    int d = rfl(deg[vi]);
    if (d == 6) {
        int ib[6];
#pragma unroll
        for (int k = 0; k < 6; k++) ib[k] = rfl(nbrB[vi * 6 + k]);
#pragma unroll
        for (int k = 0; k < 6; k++) {
            const float4* hu = h4 + (size_t)ib[k] * 4 * NBB + lane;
            float4 a0 = hu[0 * NBB], a1 = hu[1 * NBB], a2 = hu[2 * NBB], a3 = hu[3 * NBB];
            m[0]  += a0.x; m[1]  += a0.y; m[2]  += a0.z; m[3]  += a0.w;
            m[4]  += a1.x; m[5]  += a1.y; m[6]  += a1.z; m[7]  += a1.w;
            m[8]  += a2.x; m[9]  += a2.y; m[10] += a2.z; m[11] += a2.w;
            m[12] += a3.x; m[13] += a3.y; m[14] += a3.z; m[15] += a3.w;
        }
    } else {
        for (int k = 0; k < d; k++) {
            const float4* hu = h4 + (size_t)rfl(nbrB[vi * 6 + k]) * 4 * NBB + lane;
            float4 a0 = hu[0 * NBB], a1 = hu[1 * NBB], a2 = hu[2 * NBB], a3 = hu[3 * NBB];
            m[0]  += a0.x; m[1]  += a0.y; m[2]  += a0.z; m[3]  += a0.w;
            m[4]  += a1.x; m[5]  += a1.y; m[6]  += a1.z; m[7]  += a1.w;
            m[8]  += a2.x; m[9]  += a2.y; m[10] += a2.z; m[11] += a2.w;
            m[12] += a3.x; m[13] += a3.y; m[14] += a3.z; m[15] += a3.w;
        }
    }
    float inv = 1.f / (float)d;
#pragma unroll
    for (int i = 0; i < 16; i++) m[i] *= inv;
    float h2[16];
#pragma unroll
    for (int j = 0; j < 16; j++) {
        float acc = sb[j];
#pragma unroll
        for (int i = 0; i < 16; i++) acc += own[i] * sWs[i * 16 + j] + m[i] * sWn[i * 16 + j];
        h2[j] = fmaxf(acc, 0.f);
    }
    float dv[3];
#pragma unroll
    for (int c = 0; c < 3; c++) {
        float acc = sbo[c];
#pragma unroll
        for (int i = 0; i < 16; i++) acc += h2[i] * sWo[i * 3 + c];
        dv[c] = acc;
    }
    float4 n4 = feat4[((size_t)vi * 3 + 1) * NBB + lane];  // this step's normals
    float4 vv = v4[(size_t)vi * NBB + lane];
    vv.x += STEPSZ * dv[0];
    vv.y += STEPSZ * dv[1];
    vv.z += STEPSZ * dv[2];
    vv.w += STEPSZ * (n4.x * dv[0] + n4.y * dv[1] + n4.z * dv[2]);
    v4[(size_t)vi * NBB + lane] = vv;
}

// ---------------- output: (2,B,V,4) = (v*size, sulc) — coalesced reads, lane = bb ----------------
__global__ __launch_bounds__(256) void k_out(const float4* __restrict__ v4,
                                             const float* __restrict__ csz,
                                             float4* __restrict__ out) {
    int lane = threadIdx.x & 63;
    int vi = rfl(blockIdx.x * 4 + (threadIdx.x >> 6));
    if (vi >= NV) return;
    float4 o = v4[(size_t)vi * NBB + lane];
    float4 r;
    r.x = o.x * csz[(3 + 0) * NBB + lane];
    r.y = o.y * csz[(3 + 1) * NBB + lane];
    r.z = o.z * csz[(3 + 2) * NBB + lane];
    r.w = o.w;
    out[(size_t)lane * NV + vi] = r;   // lane = hemi*32 + b matches (2,B,V,4)
}

extern "C" void kernel_launch(void* const* d_in, const int* in_sizes, int n_in,
                              void* d_out, int out_size, void* d_ws, size_t ws_size,
                              hipStream_t stream) {
    const float* lh  = (const float*)d_in[0];
    const float* rh  = (const float*)d_in[1];
    const float* W1s = (const float*)d_in[2];
    const float* W1n = (const float*)d_in[3];
    const float* b1  = (const float*)d_in[4];
    const float* W2s = (const float*)d_in[5];
    const float* W2n = (const float*)d_in[6];
    const float* b2  = (const float*)d_in[7];
    const float* Wo  = (const float*)d_in[8];
    const float* bo  = (const float*)d_in[9];
    const int* faces = (const int*)d_in[10];

    float* ws    = (float*)d_ws;
    float4* v4   = (float4*)(ws + OFF_V);
    float4* ft4  = (float4*)(ws + OFF_FEAT);
    float4* h4   = (float4*)(ws + OFF_H);
    float* csz   = ws + OFF_CSZ;
    int* ibase   = (int*)(ws + OFF_INT);
    int* deg     = ibase;
    int* nbrB    = ibase + NV;
    int* nbrC    = ibase + NV + NV * 6;

    const int WPB = 4;                        // waves (vertices) per block
    dim3 gv((NV + WPB - 1) / WPB);            // 2561 blocks, wave-per-vertex

    k_zero<<<(13 * NV + 255) / 256, 256, 0, stream>>>(deg, 13 * NV);
    k_build<<<(NF + 255) / 256, 256, 0, stream>>>(faces, deg, nbrB, nbrC);
    k_norm<<<NBB, 256, 0, stream>>>(lh, rh, v4, csz);

    for (int s = 0; s < NSTEPS; s++) {
        k_geom<<<gv, 256, 0, stream>>>(v4, deg, nbrB, nbrC, ft4);
        k_layer1<<<gv, 256, 0, stream>>>(ft4, deg, nbrB, W1s, W1n, b1, h4);
        k_layer2<<<gv, 256, 0, stream>>>(h4, ft4, deg, nbrB, W2s, W2n, b2, Wo, bo, v4);
    }
    k_out<<<gv, 256, 0, stream>>>(v4, csz, (float4*)d_out);
}

// Round 2
// 1274.205 us; speedup vs baseline: 1.7699x; 1.7699x over previous
//
#include <hip/hip_runtime.h>

#define BATCH 32
#define NV    10242
#define NF    20480
#define NBB   64          // 2 hemis * 32 batches ; lane = bb
#define NSTEPS 10
#define STEPSZ 0.1f
#define EPSV   1e-8f

// ---------------- workspace layout: float4-vectorized, lane = bb ----------------
// v    : [NV][NBB] float4   (x, y, z, sulc)
// feat : [NV][3][NBB] float4 (g0: pos+pad, g1: normal+pad, g2: 0.5*lap+pad)
// h    : [NV][4][NBB] float4 (16 channels)
static constexpr size_t OFF_V    = 0;                                  // floats
static constexpr size_t OFF_FEAT = OFF_V    + (size_t)NV * NBB * 4;
static constexpr size_t OFF_H    = OFF_FEAT + (size_t)NV * NBB * 12;
static constexpr size_t OFF_CSZ  = OFF_H    + (size_t)NV * NBB * 16;   // [6][NBB] ctr(3),size(3)
static constexpr size_t OFF_INT  = OFF_CSZ  + 6 * NBB;
// int region: deg[NV], nbrB[NV*6], nbrC[NV*6]

__device__ __forceinline__ int rfl(int x) { return __builtin_amdgcn_readfirstlane(x); }

// bijective XCD chunking swizzle (contiguous vertex range per XCD; same mapping in
// geom/layer1/layer2 so cross-kernel L2 reuse lands on the same XCD)
__device__ __forceinline__ int swz(int b, int n) {
    int q = n >> 3, r = n & 7;
    int x = b & 7, i = b >> 3;
    return (x < r ? x * (q + 1) : r * (q + 1) + (x - r) * q) + i;
}

// ---------------- adjacency build (once per launch) ----------------
__global__ __launch_bounds__(256) void k_zero(int* p, int n) {
    int i = blockIdx.x * 256 + threadIdx.x;
    if (i < n) p[i] = 0;   // zeroing nbrB/nbrC too makes slot-k loads safe for deg<6 verts
}

__global__ __launch_bounds__(256) void k_build(const int* __restrict__ faces,
                                               int* deg, int* nbrB, int* nbrC) {
    int fi = blockIdx.x * 256 + threadIdx.x;
    if (fi >= NF) return;
    int vv[3] = {faces[fi * 3 + 0], faces[fi * 3 + 1], faces[fi * 3 + 2]};
#pragma unroll
    for (int c = 0; c < 3; c++) {
        int vtx = vv[c];
        int s = atomicAdd(&deg[vtx], 1);
        nbrB[vtx * 6 + s] = vv[(c + 1) % 3];   // next corner = dedup'd neighbor
        nbrC[vtx * 6 + s] = vv[(c + 2) % 3];   // prev corner
    }
}

// ---------------- bbox + normalize + transpose-in (one block per bb) ----------------
__global__ __launch_bounds__(256) void k_norm(const float* __restrict__ lh,
                                              const float* __restrict__ rh,
                                              float4* __restrict__ v4,
                                              float* __restrict__ csz) {
    int bb = blockIdx.x;
    const float* src = (bb < BATCH) ? (lh + (size_t)bb * NV * 3)
                                    : (rh + (size_t)(bb - BATCH) * NV * 3);
    __shared__ float smin[3][256], smax[3][256];
    float mn[3] = {1e30f, 1e30f, 1e30f}, mx[3] = {-1e30f, -1e30f, -1e30f};
    for (int i = threadIdx.x; i < NV; i += 256) {
#pragma unroll
        for (int c = 0; c < 3; c++) {
            float x = src[i * 3 + c];
            mn[c] = fminf(mn[c], x);
            mx[c] = fmaxf(mx[c], x);
        }
    }
#pragma unroll
    for (int c = 0; c < 3; c++) { smin[c][threadIdx.x] = mn[c]; smax[c][threadIdx.x] = mx[c]; }
    __syncthreads();
    for (int s = 128; s > 0; s >>= 1) {
        if (threadIdx.x < s) {
#pragma unroll
            for (int c = 0; c < 3; c++) {
                smin[c][threadIdx.x] = fminf(smin[c][threadIdx.x], smin[c][threadIdx.x + s]);
                smax[c][threadIdx.x] = fmaxf(smax[c][threadIdx.x], smax[c][threadIdx.x + s]);
            }
        }
        __syncthreads();
    }
    float ctr[3], sz[3];
#pragma unroll
    for (int c = 0; c < 3; c++) {
        ctr[c] = 0.5f * (smin[c][0] + smax[c][0]);
        sz[c]  = smax[c][0] - ctr[c];
    }
    if (threadIdx.x == 0) {
#pragma unroll
        for (int c = 0; c < 3; c++) { csz[c * NBB + bb] = ctr[c]; csz[(3 + c) * NBB + bb] = sz[c]; }
    }
    for (int i = threadIdx.x; i < NV; i += 256) {
        float4 o;
        o.x = (src[i * 3 + 0] - ctr[0]) / sz[0];
        o.y = (src[i * 3 + 1] - ctr[1]) / sz[1];
        o.z = (src[i * 3 + 2] - ctr[2]) / sz[2];
        o.w = 0.f;                               // sulc lives in v.w
        v4[(size_t)i * NBB + bb] = o;
    }
}

// ---------------- per-step: geometry -> feat = (v | n | 0.5*lap), float4 groups ----------------
// NOTE: no min-waves clamp — round-1's (256,4) forced 64 VGPRs -> massive scratch spill
// (WRITE_SIZE 10 MB -> 427 MB). Let the allocator keep the working set in registers.
__global__ __launch_bounds__(256) void k_geom(const float4* __restrict__ v4,
                                              const int* __restrict__ deg,
                                              const int* __restrict__ nbrB,
                                              const int* __restrict__ nbrC,
                                              float4* __restrict__ feat4) {
    int lane = threadIdx.x & 63;
    int blk = swz(blockIdx.x, gridDim.x);
    int vi = rfl(blk * 4 + (threadIdx.x >> 6));
    if (vi >= NV) return;
    float sgn = (lane < BATCH) ? 1.f : -1.f;   // rh: reversed winding flips face normals
    float4 a = v4[(size_t)vi * NBB + lane];
    int d = rfl(deg[vi]);
    float vnx = 0.f, vny = 0.f, vnz = 0.f, lx = 0.f, ly = 0.f, lz = 0.f;

    auto acc = [&](float4 b, float4 c) {
        float e1x = b.x - a.x, e1y = b.y - a.y, e1z = b.z - a.z;   // B - A
        float e2x = c.x - a.x, e2y = c.y - a.y, e2z = c.z - a.z;   // C - A
        float fnx = e1y * e2z - e1z * e2y;                         // face normal
        float fny = e1z * e2x - e1x * e2z;
        float fnz = e1x * e2y - e1y * e2x;
        vnx += fnx; vny += fny; vnz += fnz;
        float rd = 1.f / (sqrtf(fnx * fnx + fny * fny + fnz * fnz) + EPSV);
        float ux = c.x - b.x, uy = c.y - b.y, uz = c.z - b.z;
        float wx = a.x - b.x, wy = a.y - b.y, wz = a.z - b.z;
        float cB = (ux * wx + uy * wy + uz * wz) * rd;             // cot at B
        float rx = a.x - c.x, ry = a.y - c.y, rz = a.z - c.z;
        float sx = b.x - c.x, sy = b.y - c.y, sz2 = b.z - c.z;
        float cC = (rx * sx + ry * sy + rz * sz2) * rd;            // cot at C
        lx += cC * e1x + cB * e2x;
        ly += cC * e1y + cB * e2y;
        lz += cC * e1z + cB * e2z;
    };

    if (d == 6) {
        int ib[6], ic[6];
#pragma unroll
        for (int k = 0; k < 6; k++) {
            ib[k] = rfl(nbrB[vi * 6 + k]);
            ic[k] = rfl(nbrC[vi * 6 + k]);
        }
        // two half-batches of 3 faces: 6 float4 loads in flight (~24 VGPRs of data),
        // enough MLP to hide latency without blowing the register budget
#pragma unroll
        for (int g = 0; g < 2; g++) {
            float4 pb[3], pc[3];
#pragma unroll
            for (int k = 0; k < 3; k++) {
                pb[k] = v4[(size_t)ib[g * 3 + k] * NBB + lane];
                pc[k] = v4[(size_t)ic[g * 3 + k] * NBB + lane];
            }
#pragma unroll
            for (int k = 0; k < 3; k++) acc(pb[k], pc[k]);
        }
    } else {
        for (int k = 0; k < d; k++) {
            int iB = rfl(nbrB[vi * 6 + k]);
            int iC = rfl(nbrC[vi * 6 + k]);
            acc(v4[(size_t)iB * NBB + lane], v4[(size_t)iC * NBB + lane]);
        }
    }
    vnx *= sgn; vny *= sgn; vnz *= sgn;
    float nn = 1.f / (sqrtf(vnx * vnx + vny * vny + vnz * vnz) + EPSV);
    float4* fp = feat4 + (size_t)vi * 3 * NBB + lane;
    fp[0 * NBB] = make_float4(a.x, a.y, a.z, 0.f);
    fp[1 * NBB] = make_float4(vnx * nn, vny * nn, vnz * nn, 0.f);
    fp[2 * NBB] = make_float4(0.5f * lx, 0.5f * ly, 0.5f * lz, 0.f);
}

// ---------------- per-step: layer1  h = relu(feat@W1s + mean_nbr(feat)@W1n + b1) ----------------
__global__ __launch_bounds__(256) void k_layer1(const float4* __restrict__ feat4,
                                                const int* __restrict__ deg,
                                                const int* __restrict__ nbrB,
                                                const float* __restrict__ W1s,
                                                const float* __restrict__ W1n,
                                                const float* __restrict__ b1,
                                                float4* __restrict__ h4) {
    __shared__ float sWs[144], sWn[144], sb[16];
    int t = threadIdx.x;
    if (t < 144) { sWs[t] = W1s[t]; sWn[t] = W1n[t]; }
    if (t < 16) sb[t] = b1[t];
    __syncthreads();
    int lane = t & 63;
    int blk = swz(blockIdx.x, gridDim.x);
    int vi = rfl(blk * 4 + (t >> 6));
    if (vi >= NV) return;
    const float4* fo = feat4 + (size_t)vi * 3 * NBB + lane;
    float4 f0 = fo[0 * NBB], f1 = fo[1 * NBB], f2 = fo[2 * NBB];
    float own[9] = {f0.x, f0.y, f0.z, f1.x, f1.y, f1.z, f2.x, f2.y, f2.z};
    float m[9] = {0.f, 0.f, 0.f, 0.f, 0.f, 0.f, 0.f, 0.f, 0.f};
    int d = rfl(deg[vi]);
    if (d == 6) {
        int ib[6];
#pragma unroll
        for (int k = 0; k < 6; k++) ib[k] = rfl(nbrB[vi * 6 + k]);
#pragma unroll
        for (int k = 0; k < 6; k++) {
            const float4* fu = feat4 + (size_t)ib[k] * 3 * NBB + lane;
            float4 a0 = fu[0 * NBB], a1 = fu[1 * NBB], a2 = fu[2 * NBB];
            m[0] += a0.x; m[1] += a0.y; m[2] += a0.z;
            m[3] += a1.x; m[4] += a1.y; m[5] += a1.z;
            m[6] += a2.x; m[7] += a2.y; m[8] += a2.z;
        }
    } else {
        for (int k = 0; k < d; k++) {
            const float4* fu = feat4 + (size_t)rfl(nbrB[vi * 6 + k]) * 3 * NBB + lane;
            float4 a0 = fu[0 * NBB], a1 = fu[1 * NBB], a2 = fu[2 * NBB];
            m[0] += a0.x; m[1] += a0.y; m[2] += a0.z;
            m[3] += a1.x; m[4] += a1.y; m[5] += a1.z;
            m[6] += a2.x; m[7] += a2.y; m[8] += a2.z;
        }
    }
    float inv = 1.f / (float)d;
#pragma unroll
    for (int i = 0; i < 9; i++) m[i] *= inv;
    float hv[16];
#pragma unroll
    for (int j = 0; j < 16; j++) {
        float acc = sb[j];
#pragma unroll
        for (int i = 0; i < 9; i++) acc += own[i] * sWs[i * 16 + j] + m[i] * sWn[i * 16 + j];
        hv[j] = fmaxf(acc, 0.f);
    }
    float4* hp = h4 + (size_t)vi * 4 * NBB + lane;
#pragma unroll
    for (int g = 0; g < 4; g++)
        hp[g * NBB] = make_float4(hv[g * 4 + 0], hv[g * 4 + 1], hv[g * 4 + 2], hv[g * 4 + 3]);
}

// ---------------- per-step: layer2 + output head + state update (sulc in v.w) ----------------
__global__ __launch_bounds__(256) void k_layer2(const float4* __restrict__ h4,
                                                const float4* __restrict__ feat4,
                                                const int* __restrict__ deg,
                                                const int* __restrict__ nbrB,
                                                const float* __restrict__ W2s,
                                                const float* __restrict__ W2n,
                                                const float* __restrict__ b2,
                                                const float* __restrict__ Wo,
                                                const float* __restrict__ bo,
                                                float4* __restrict__ v4) {
    __shared__ float sWs[256], sWn[256], sb[16], sWo[48], sbo[3];
    int t = threadIdx.x;
    sWs[t] = W2s[t];
    sWn[t] = W2n[t];
    if (t < 16) sb[t] = b2[t];
    if (t < 48) sWo[t] = Wo[t];
    if (t < 3) sbo[t] = bo[t];
    __syncthreads();
    int lane = t & 63;
    int blk = swz(blockIdx.x, gridDim.x);
    int vi = rfl(blk * 4 + (t >> 6));
    if (vi >= NV) return;
    const float4* ho = h4 + (size_t)vi * 4 * NBB + lane;
    float own[16], m[16];
#pragma unroll
    for (int g = 0; g < 4; g++) {
        float4 o = ho[g * NBB];
        own[g * 4 + 0] = o.x; own[g * 4 + 1] = o.y; own[g * 4 + 2] = o.z; own[g * 4 + 3] = o.w;
        m[g * 4 + 0] = 0.f; m[g * 4 + 1] = 0.f; m[g * 4 + 2] = 0.f; m[g * 4 + 3] = 0.f;
    }
    int d = rfl(deg[vi]);
    if (d == 6) {
        int ib[6];
#pragma unroll
        for (int k = 0; k < 6; k++) ib[k] = rfl(nbrB[vi * 6 + k]);
        // 2 neighbors in flight at a time: 8 float4 (~32 VGPRs) of gather data
#pragma unroll
        for (int g = 0; g < 3; g++) {
            const float4* hu0 = h4 + (size_t)ib[g * 2 + 0] * 4 * NBB + lane;
            const float4* hu1 = h4 + (size_t)ib[g * 2 + 1] * 4 * NBB + lane;
            float4 a0 = hu0[0 * NBB], a1 = hu0[1 * NBB], a2 = hu0[2 * NBB], a3 = hu0[3 * NBB];
            float4 b0 = hu1[0 * NBB], b1 = hu1[1 * NBB], b2_ = hu1[2 * NBB], b3 = hu1[3 * NBB];
            m[0]  += a0.x + b0.x; m[1]  += a0.y + b0.y; m[2]  += a0.z + b0.z; m[3]  += a0.w + b0.w;
            m[4]  += a1.x + b1.x; m[5]  += a1.y + b1.y; m[6]  += a1.z + b1.z; m[7]  += a1.w + b1.w;
            m[8]  += a2.x + b2_.x; m[9] += a2.y + b2_.y; m[10] += a2.z + b2_.z; m[11] += a2.w + b2_.w;
            m[12] += a3.x + b3.x; m[13] += a3.y + b3.y; m[14] += a3.z + b3.z; m[15] += a3.w + b3.w;
        }
    } else {
        for (int k = 0; k < d; k++) {
            const float4* hu = h4 + (size_t)rfl(nbrB[vi * 6 + k]) * 4 * NBB + lane;
            float4 a0 = hu[0 * NBB], a1 = hu[1 * NBB], a2 = hu[2 * NBB], a3 = hu[3 * NBB];
            m[0]  += a0.x; m[1]  += a0.y; m[2]  += a0.z; m[3]  += a0.w;
            m[4]  += a1.x; m[5]  += a1.y; m[6]  += a1.z; m[7]  += a1.w;
            m[8]  += a2.x; m[9]  += a2.y; m[10] += a2.z; m[11] += a2.w;
            m[12] += a3.x; m[13] += a3.y; m[14] += a3.z; m[15] += a3.w;
        }
    }
    float inv = 1.f / (float)d;
#pragma unroll
    for (int i = 0; i < 16; i++) m[i] *= inv;
    float h2[16];
#pragma unroll
    for (int j = 0; j < 16; j++) {
        float acc = sb[j];
#pragma unroll
        for (int i = 0; i < 16; i++) acc += own[i] * sWs[i * 16 + j] + m[i] * sWn[i * 16 + j];
        h2[j] = fmaxf(acc, 0.f);
    }
    float dv[3];
#pragma unroll
    for (int c = 0; c < 3; c++) {
        float acc = sbo[c];
#pragma unroll
        for (int i = 0; i < 16; i++) acc += h2[i] * sWo[i * 3 + c];
        dv[c] = acc;
    }
    float4 n4 = feat4[((size_t)vi * 3 + 1) * NBB + lane];  // this step's normals
    float4 vv = v4[(size_t)vi * NBB + lane];
    vv.x += STEPSZ * dv[0];
    vv.y += STEPSZ * dv[1];
    vv.z += STEPSZ * dv[2];
    vv.w += STEPSZ * (n4.x * dv[0] + n4.y * dv[1] + n4.z * dv[2]);
    v4[(size_t)vi * NBB + lane] = vv;
}

// ---------------- output: (2,B,V,4) = (v*size, sulc) — coalesced reads, lane = bb ----------------
__global__ __launch_bounds__(256) void k_out(const float4* __restrict__ v4,
                                             const float* __restrict__ csz,
                                             float4* __restrict__ out) {
    int lane = threadIdx.x & 63;
    int vi = rfl(blockIdx.x * 4 + (threadIdx.x >> 6));
    if (vi >= NV) return;
    float4 o = v4[(size_t)vi * NBB + lane];
    float4 r;
    r.x = o.x * csz[(3 + 0) * NBB + lane];
    r.y = o.y * csz[(3 + 1) * NBB + lane];
    r.z = o.z * csz[(3 + 2) * NBB + lane];
    r.w = o.w;
    out[(size_t)lane * NV + vi] = r;   // lane = hemi*32 + b matches (2,B,V,4)
}

extern "C" void kernel_launch(void* const* d_in, const int* in_sizes, int n_in,
                              void* d_out, int out_size, void* d_ws, size_t ws_size,
                              hipStream_t stream) {
    const float* lh  = (const float*)d_in[0];
    const float* rh  = (const float*)d_in[1];
    const float* W1s = (const float*)d_in[2];
    const float* W1n = (const float*)d_in[3];
    const float* b1  = (const float*)d_in[4];
    const float* W2s = (const float*)d_in[5];
    const float* W2n = (const float*)d_in[6];
    const float* b2  = (const float*)d_in[7];
    const float* Wo  = (const float*)d_in[8];
    const float* bo  = (const float*)d_in[9];
    const int* faces = (const int*)d_in[10];

    float* ws    = (float*)d_ws;
    float4* v4   = (float4*)(ws + OFF_V);
    float4* ft4  = (float4*)(ws + OFF_FEAT);
    float4* h4   = (float4*)(ws + OFF_H);
    float* csz   = ws + OFF_CSZ;
    int* ibase   = (int*)(ws + OFF_INT);
    int* deg     = ibase;
    int* nbrB    = ibase + NV;
    int* nbrC    = ibase + NV + NV * 6;

    const int WPB = 4;                        // waves (vertices) per block
    dim3 gv((NV + WPB - 1) / WPB);            // 2561 blocks, wave-per-vertex

    k_zero<<<(13 * NV + 255) / 256, 256, 0, stream>>>(deg, 13 * NV);
    k_build<<<(NF + 255) / 256, 256, 0, stream>>>(faces, deg, nbrB, nbrC);
    k_norm<<<NBB, 256, 0, stream>>>(lh, rh, v4, csz);

    for (int s = 0; s < NSTEPS; s++) {
        k_geom<<<gv, 256, 0, stream>>>(v4, deg, nbrB, nbrC, ft4);
        k_layer1<<<gv, 256, 0, stream>>>(ft4, deg, nbrB, W1s, W1n, b1, h4);
        k_layer2<<<gv, 256, 0, stream>>>(h4, ft4, deg, nbrB, W2s, W2n, b2, Wo, bo, v4);
    }
    k_out<<<gv, 256, 0, stream>>>(v4, csz, (float4*)d_out);
}